// Round 14
// baseline (220.326 us; speedup 1.0000x reference)
//
#include <hip/hip_runtime.h>

// GAT batch: B=32, N=512, Fin=128, Fhid=64, H=8, C=16.  fp32 I/O.
// R27: attn1 v14 — BARRIER-FREE main loop. Score-gen re-mapped so lane
//   (c,q) computes its own MFMA A-fragment (row c, cols kk*32+q*8):
//   P never touches LDS; no per-phase __syncthreads -> the 4 waves/SIMD
//   run at independent phases and interleave stalls (previous structure:
//   barrier-locked convoy, 11.5K cyc/phase vs 1.5K issue).
//   E2/e2 in a 2KB LDS table (one init barrier); masks 4xb128 per tile
//   (byte q of dword kk = exactly the 8 bits lane needs); E1 per-lane
//   load+exp (no readlane). Epilogue/C-layout unchanged.
// (K1 R25 int4-pack + 64-row gemm; K3/K4 reverted to R25 forms —
//  R26's K-split was null, confirming K3/K4 are small.)
#define GB 32
#define GN 512
#define GFIN 128
#define GFH 64
#define GH 8
#define GC 16

typedef short short8 __attribute__((ext_vector_type(8)));   // 8 fp16 bits (MFMA A/B frag)
typedef float f32x4 __attribute__((ext_vector_type(4)));    // MFMA C/D frag
typedef _Float16 h2 __attribute__((ext_vector_type(2)));
typedef _Float16 half8 __attribute__((ext_vector_type(8)));

__device__ __forceinline__ ushort f2h(float f) {
  _Float16 h = (_Float16)f;                 // v_cvt_f16_f32 (RNE), 1 inst
  return __builtin_bit_cast(ushort, h);
}
__device__ __forceinline__ h2 cvt_pk(float a, float b) {
  return __builtin_bit_cast(h2, __builtin_amdgcn_cvt_pkrtz(a, b));
}
__device__ __forceinline__ unsigned pkh2(float a, float b) {
  return __builtin_bit_cast(unsigned, __builtin_amdgcn_cvt_pkrtz(a, b));
}
__device__ __forceinline__ short8 ones8() {
  short8 o;
#pragma unroll
  for (int i = 0; i < 8; ++i) o[i] = (short)0x3C00;  // fp16 1.0
  return o;
}
// Fast a/b: v_rcp_f32 (1 ulp) + mul — result feeds fp16, noise-level error.
__device__ __forceinline__ float fdiv_fast(float a, float b) {
  return a * __builtin_amdgcn_rcpf(b);
}
__device__ __forceinline__ f32x4 mfma_h(short8 a, short8 b, f32x4 c) {
  return __builtin_amdgcn_mfma_f32_16x16x32_f16(
      __builtin_bit_cast(half8, a), __builtin_bit_cast(half8, b), c, 0, 0, 0);
}

// 8 masked fp16 scores (4 packed pairs) for one row of 8 consecutive cols.
__device__ __forceinline__ uint4 score8(unsigned E1u, unsigned e1u,
                                        const h2* E2h, const h2* e2h,
                                        unsigned mb) {
  h2 E1h = __builtin_bit_cast(h2, E1u);
  h2 e1h = __builtin_bit_cast(h2, e1u);
  unsigned lo = (((mb & 0xFu) * 0x00204081u) & 0x01010101u) * 0xFFu;
  unsigned hi = (((mb >> 4) * 0x00204081u) & 0x01010101u) * 0xFFu;
  unsigned m0 = __builtin_amdgcn_perm(lo, lo, 0x01010000u);
  unsigned m1 = __builtin_amdgcn_perm(lo, lo, 0x03030202u);
  unsigned m2 = __builtin_amdgcn_perm(hi, hi, 0x01010000u);
  unsigned m3 = __builtin_amdgcn_perm(hi, hi, 0x03030202u);
  uint4 u;
  u.x = __builtin_bit_cast(unsigned,
          __builtin_elementwise_max(E1h * E2h[0], e1h * e2h[0])) & m0;
  u.y = __builtin_bit_cast(unsigned,
          __builtin_elementwise_max(E1h * E2h[1], e1h * e2h[1])) & m1;
  u.z = __builtin_bit_cast(unsigned,
          __builtin_elementwise_max(E1h * E2h[2], e1h * e2h[2])) & m2;
  u.w = __builtin_bit_cast(unsigned,
          __builtin_elementwise_max(E1h * E2h[3], e1h * e2h[3])) & m3;
  return u;
}

// ---------------------------------------------------------------------------
// K1: blocks [0,4096): adj bit-pack (int4 + shfl-OR; dispatched FIRST).
// Blocks [4096,6144): gemm1, 64 rows/block (V^T fp16 + fp32 f1/f2).
// Block 6144: W_out -> WoT fp16.
// ---------------------------------------------------------------------------
__global__ __launch_bounds__(256) void k_pack_gemm1(
    const int* __restrict__ adj, unsigned* __restrict__ mw,
    const float* __restrict__ xg, const float* __restrict__ Wg,
    const float* __restrict__ a1g, const float* __restrict__ a2g,
    ushort* __restrict__ VTg, float* __restrict__ f1g, float* __restrict__ f2g,
    const float* __restrict__ Wog, ushort* __restrict__ WoT) {
  __shared__ ushort Wt[64][136];
  __shared__ ushort xl[64][136];
  int blk = blockIdx.x;
  int tid = threadIdx.x;

  if (blk == 6144) {
    for (int i = tid; i < 512 * GC; i += 256) {
      int k = i & 511, cc = i >> 9;
      WoT[cc * 512 + k] = f2h(Wog[(size_t)k * GC + cc]);
    }
    return;
  }
  if (blk < 4096) {                      // adj pack (HBM/L3 long pole)
    int pblk = blk;
    int4 v0 = *(const int4*)&adj[(size_t)pblk * 2048 + tid * 4];
    int4 v1 = *(const int4*)&adj[(size_t)pblk * 2048 + 1024 + tid * 4];
    int sh = 4 * (tid & 7);
    unsigned b0 = ((v0.x > 0) ? 1u : 0u) | ((v0.y > 0) ? 2u : 0u) |
                  ((v0.z > 0) ? 4u : 0u) | ((v0.w > 0) ? 8u : 0u);
    unsigned b1 = ((v1.x > 0) ? 1u : 0u) | ((v1.y > 0) ? 2u : 0u) |
                  ((v1.z > 0) ? 4u : 0u) | ((v1.w > 0) ? 8u : 0u);
    unsigned m0 = b0 << sh, m1 = b1 << sh;
    m0 |= __shfl_xor(m0, 1); m1 |= __shfl_xor(m1, 1);
    m0 |= __shfl_xor(m0, 2); m1 |= __shfl_xor(m1, 2);
    m0 |= __shfl_xor(m0, 4); m1 |= __shfl_xor(m1, 4);
    if ((tid & 7) == 0) {
      mw[pblk * 64 + (tid >> 3)] = m0;
      mw[pblk * 64 + 32 + (tid >> 3)] = m1;
    }
    return;
  }

  int gblk = blk - 4096;                 // gemm1: [0,2048), 64 rows each
  int bh = gblk >> 3, rs8 = gblk & 7;
  int b = bh >> 3, h = bh & 7;
  int r0 = rs8 * 64;
  int lane = tid & 63, w = tid >> 6;
  int c = lane & 15, q = lane >> 4;

  // W staging vectorized: 8 float4 iters/thread.
  const float* Wh = Wg + (size_t)h * GFIN * GFH;
  for (int u4 = tid; u4 < GFIN * GFH / 4; u4 += 256) {
    int i0 = u4 * 4;
    int f = i0 >> 6, j0 = i0 & 63;       // 4 | 64 -> all 4 share f
    float4 wv = *(const float4*)&Wh[i0];
    Wt[j0 + 0][f] = f2h(wv.x);
    Wt[j0 + 1][f] = f2h(wv.y);
    Wt[j0 + 2][f] = f2h(wv.z);
    Wt[j0 + 3][f] = f2h(wv.w);
  }
  const float* xb = xg + ((size_t)b * GN + r0) * GFIN;
  for (int u = tid; u < 64 * 32; u += 256) {
    int row = u >> 5, c4 = u & 31;
    float4 xf = *(const float4*)&xb[(size_t)row * GFIN + c4 * 4];
    uint2 us;
    us.x = pkh2(xf.x, xf.y);
    us.y = pkh2(xf.z, xf.w);
    *(uint2*)&xl[row][c4 * 4] = us;
  }
  __syncthreads();

  short8 Bf[4][4];
#pragma unroll
  for (int cb = 0; cb < 4; ++cb)
#pragma unroll
    for (int kk = 0; kk < 4; ++kk)
      Bf[cb][kk] = *(const short8*)&Wt[cb * 16 + c][kk * 32 + q * 8];

  float a1v[4], a2v[4];
#pragma unroll
  for (int cb = 0; cb < 4; ++cb) {
    a1v[cb] = a1g[h * 64 + cb * 16 + c];
    a2v[cb] = a2g[h * 64 + cb * 16 + c];
  }

  f32x4 acc[4];
#pragma unroll
  for (int cb = 0; cb < 4; ++cb) acc[cb] = (f32x4){0.f, 0.f, 0.f, 0.f};

#pragma unroll
  for (int kk = 0; kk < 4; ++kk) {
    short8 A = *(const short8*)&xl[w * 16 + c][kk * 32 + q * 8];
#pragma unroll
    for (int cb = 0; cb < 4; ++cb)
      acc[cb] = mfma_h(A, Bf[cb][kk], acc[cb]);
  }

  ushort* VT = VTg + (size_t)bh * GN * GFH;
  float* f1o = f1g + (size_t)bh * GN;
  float* f2o = f2g + (size_t)bh * GN;
  int rowb = r0 + w * 16 + q * 4;
  float v1[4] = {0.f, 0.f, 0.f, 0.f}, v2[4] = {0.f, 0.f, 0.f, 0.f};
#pragma unroll
  for (int cb = 0; cb < 4; ++cb) {
    f32x4 a = acc[cb];
    uint2 vs;
    vs.x = pkh2(a[0], a[1]);
    vs.y = pkh2(a[2], a[3]);
    *(uint2*)&VT[(size_t)(cb * 16 + c) * GN + rowb] = vs;
#pragma unroll
    for (int i = 0; i < 4; ++i) {
      v1[i] += a[i] * a1v[cb];
      v2[i] += a[i] * a2v[cb];
    }
  }
#pragma unroll
  for (int i = 0; i < 4; ++i) {
#pragma unroll
    for (int off = 1; off < 16; off <<= 1) {
      v1[i] += __shfl_xor(v1[i], off);
      v2[i] += __shfl_xor(v2[i], off);
    }
    if (c == 0) { f1o[rowb + i] = v1[i]; f2o[rowb + i] = v2[i]; }
  }
}

// ---------------------------------------------------------------------------
// K2: layer-1 attention v14 — barrier-free main loop. Lane (c,q) computes
// its own A-fragment (row c, cols kk*32+q*8) directly from the 2KB LDS
// exp-table + per-lane mask dwords; MFMA consumes it immediately. One
// barrier total (after table init). grid 1024 = slice*256 + bh.
// ---------------------------------------------------------------------------
__global__ __launch_bounds__(256) void k_attn1(
    const ushort* __restrict__ VTg, const unsigned* __restrict__ mwg,
    const float* __restrict__ f1g, const float* __restrict__ f2g,
    ushort* __restrict__ xcb) {
  __shared__ h2 etab[2][64][4];          // [E2|e2][col-group g][4 pairs]
  int blk = blockIdx.x;
  int bh = blk & 255, slice = blk >> 8;  // slice 0..3
  int b = bh >> 3, h = bh & 7;
  int r0 = slice * 128;
  int tid = threadIdx.x, lane = tid & 63, w = tid >> 6;
  int c = lane & 15, q = lane >> 4;

  const unsigned* mwb = mwg + (size_t)b * GN * 16;
  const float* f1w = f1g + (size_t)bh * GN;
  const float* f2w = f2g + (size_t)bh * GN;

  // exp tables: 512 cols, pairs packed fp16. e^-4 folded into the f1 side
  // later (range safety, ratio invariant).
  {
    int col0 = tid * 2;
    float a = f2w[col0], bb = f2w[col0 + 1];
    etab[0][col0 >> 3][(col0 >> 1) & 3] = cvt_pk(__expf(a), __expf(bb));
    etab[1][col0 >> 3][(col0 >> 1) & 3] =
        cvt_pk(__expf(0.2f * a), __expf(0.2f * bb));
  }

  const ushort* VT = VTg + (size_t)bh * GN * GFH + (size_t)(w * 16 + c) * GN + q * 8;
  short8 Bf[16];
#pragma unroll
  for (int kk = 0; kk < 16; ++kk) Bf[kk] = *(const short8*)&VT[kk * 32];
  const short8 ONES = ones8();
  __syncthreads();                       // table ready; ONLY barrier.

  ushort* xo = xcb + ((size_t)b * GN) * 512 + h * 64 + w * 16 + c;
#pragma unroll
  for (int t = 0; t < 8; ++t) {
    int tb = r0 + t * 16;
    int mrow = tb + c;                   // this lane's score row
    float f1v = f1w[mrow];
    unsigned E1u = pkh2(__expf(f1v - 4.f), __expf(f1v - 4.f));
    unsigned e1u = pkh2(__expf(0.2f * f1v - 4.f), __expf(0.2f * f1v - 4.f));
    uint4 mA = *(const uint4*)&mwb[(size_t)mrow * 16 + 0];
    uint4 mB = *(const uint4*)&mwb[(size_t)mrow * 16 + 4];
    uint4 mC = *(const uint4*)&mwb[(size_t)mrow * 16 + 8];
    uint4 mD = *(const uint4*)&mwb[(size_t)mrow * 16 + 12];
    unsigned mn[16] = {mA.x, mA.y, mA.z, mA.w, mB.x, mB.y, mB.z, mB.w,
                       mC.x, mC.y, mC.z, mC.w, mD.x, mD.y, mD.z, mD.w};

    f32x4 acc = (f32x4){0.f, 0.f, 0.f, 0.f};
    f32x4 aL = (f32x4){0.f, 0.f, 0.f, 0.f};
#pragma unroll
    for (int kk = 0; kk < 16; ++kk) {
      int g = kk * 4 + q;
      uint4 ue = *(const uint4*)&etab[0][g][0];
      uint4 uf = *(const uint4*)&etab[1][g][0];
      h2 E2l[4] = {__builtin_bit_cast(h2, ue.x), __builtin_bit_cast(h2, ue.y),
                   __builtin_bit_cast(h2, ue.z), __builtin_bit_cast(h2, ue.w)};
      h2 e2l[4] = {__builtin_bit_cast(h2, uf.x), __builtin_bit_cast(h2, uf.y),
                   __builtin_bit_cast(h2, uf.z), __builtin_bit_cast(h2, uf.w)};
      unsigned mb = (mn[kk] >> (8 * q)) & 0xffu;
      uint4 u = score8(E1u, e1u, E2l, e2l, mb);
      short8 A = __builtin_bit_cast(short8, u);
      acc = mfma_h(A, Bf[kk], acc);
      aL  = mfma_h(A, ONES, aL);
    }

#pragma unroll
    for (int i = 0; i < 4; ++i) {
      int row = tb + q * 4 + i;
      float v = fdiv_fast(acc[i], fmaxf(aL[i], 1e-30f));
      v = v > 0.f ? v : __expf(v) - 1.f;            // elu
      xo[(size_t)row * 512] = f2h(v);
    }
  }
}

// ---------------------------------------------------------------------------
// K3: gemm2 via MFMA, A-frags straight from L2-resident xcb. grid = 256.
// ---------------------------------------------------------------------------
__global__ __launch_bounds__(256) void k_gemm2(
    const ushort* __restrict__ xcb, const ushort* __restrict__ WoT,
    const float* __restrict__ a1o, const float* __restrict__ a2o,
    ushort* __restrict__ hTg, float* __restrict__ f1bg,
    float* __restrict__ f2bg) {
  int vb = blockIdx.x;
  int b = vb >> 3, r0 = (vb & 7) * 64;
  int tid = threadIdx.x, lane = tid & 63, w = tid >> 6;
  int c = lane & 15, q = lane >> 4;

  short8 Bf[16];
#pragma unroll
  for (int kk = 0; kk < 16; ++kk)
    Bf[kk] = *(const short8*)&WoT[(size_t)c * 512 + kk * 32 + q * 8];

  const ushort* xrow = xcb + ((size_t)(b * GN + r0 + w * 16 + c)) * 512 + q * 8;
  f32x4 acc = (f32x4){0.f, 0.f, 0.f, 0.f};
#pragma unroll
  for (int kk = 0; kk < 16; ++kk) {
    short8 A = *(const short8*)&xrow[kk * 32];
    acc = mfma_h(A, Bf[kk], acc);
  }

  float a1v = a1o[c], a2v = a2o[c];
  int rowb = r0 + w * 16 + q * 4;
  uint2 vs;
  vs.x = pkh2(acc[0], acc[1]);
  vs.y = pkh2(acc[2], acc[3]);
  *(uint2*)&hTg[((size_t)b * GC + c) * 512 + rowb] = vs;
#pragma unroll
  for (int i = 0; i < 4; ++i) {
    float v1 = acc[i] * a1v, v2 = acc[i] * a2v;
#pragma unroll
    for (int off = 1; off < 16; off <<= 1) {
      v1 += __shfl_xor(v1, off);
      v2 += __shfl_xor(v2, off);
    }
    if (c == 0) {
      f1bg[(size_t)b * GN + rowb + i] = v1;
      f2bg[(size_t)b * GN + rowb + i] = v2;
    }
  }
}

// ---------------------------------------------------------------------------
// K4: layer-2 attention: grid = 512 (b*16 + 32-row tile). ALL 4 waves
// in the MFMA phase via K-split: wave w computes tile (w&1) over K-half
// (w>>1) (8+8 MFMAs); partials combined via 4KB LDS.
// ---------------------------------------------------------------------------
__global__ __launch_bounds__(256) void k_attn2(
    const ushort* __restrict__ hTg, const unsigned* __restrict__ mwg,
    const float* __restrict__ f1g, const float* __restrict__ f2g,
    float* __restrict__ outg) {
  __shared__ ushort P[32][520];
  __shared__ float pacc[2][64][8];     // [tile][lane][acc0..3, aL0..3]
  int vb = blockIdx.x;
  int b = vb >> 4, r0 = (vb & 15) * 32;
  int tid = threadIdx.x, lane = tid & 63, w = tid >> 6;
  int c = lane & 15, q = lane >> 4;
  const short8 ONES = ones8();

  const unsigned* mwb = mwg + (size_t)b * GN * 16;
  const float* f1w = f1g + (size_t)b * GN;
  const float* f2w = f2g + (size_t)b * GN;

  float4 fa = *(const float4*)&f2w[lane * 8];
  float4 fb = *(const float4*)&f2w[lane * 8 + 4];
  h2 E2h[4], e2h[4];
  {
    float f2v[8] = {fa.x, fa.y, fa.z, fa.w, fb.x, fb.y, fb.z, fb.w};
#pragma unroll
    for (int j = 0; j < 4; ++j) {
      E2h[j] = cvt_pk(__expf(f2v[2 * j]), __expf(f2v[2 * j + 1]));
      e2h[j] = cvt_pk(__expf(0.2f * f2v[2 * j]), __expf(0.2f * f2v[2 * j + 1]));
    }
  }
  float f1v = 0.f;
  if (lane < 8) f1v = f1w[r0 + w * 8 + lane];
  float E1f = __expf(f1v - 4.f), e1f = __expf(0.2f * f1v - 4.f);
  unsigned E1pk = pkh2(E1f, E1f);
  unsigned e1pk = pkh2(e1f, e1f);

  unsigned mword[8];
#pragma unroll
  for (int ri = 0; ri < 8; ++ri)
    mword[ri] = mwb[(size_t)(r0 + w * 8 + ri) * 16 + (lane >> 2)];
#pragma unroll
  for (int ri = 0; ri < 8; ++ri) {
    unsigned E1u = (unsigned)__builtin_amdgcn_readlane((int)E1pk, ri);
    unsigned e1u = (unsigned)__builtin_amdgcn_readlane((int)e1pk, ri);
    unsigned mb = (mword[ri] >> (8 * (lane & 3))) & 0xffu;
    uint4 u = score8(E1u, e1u, E2h, e2h, mb);
    *(uint4*)&P[w * 8 + ri][lane * 8] = u;
  }
  __syncthreads();

  int tile = w & 1, kh = w >> 1;       // tile 0/1, K-half 0/1
  short8 Bf[8];
#pragma unroll
  for (int kk = 0; kk < 8; ++kk)
    Bf[kk] = *(const short8*)&hTg[((size_t)b * GC + c) * 512 +
                                  (kh * 8 + kk) * 32 + q * 8];
  f32x4 acc = (f32x4){0.f, 0.f, 0.f, 0.f};
  f32x4 aL = (f32x4){0.f, 0.f, 0.f, 0.f};
#pragma unroll
  for (int kk = 0; kk < 8; ++kk) {
    short8 A = *(const short8*)&P[tile * 16 + c][(kh * 8 + kk) * 32 + q * 8];
    acc = mfma_h(A, Bf[kk], acc);
    aL  = mfma_h(A, ONES, aL);
  }
  if (kh == 1) {
#pragma unroll
    for (int i = 0; i < 4; ++i) {
      pacc[tile][lane][i] = acc[i];
      pacc[tile][lane][4 + i] = aL[i];
    }
  }
  __syncthreads();
  if (kh == 0) {
#pragma unroll
    for (int i = 0; i < 4; ++i) {
      acc[i] += pacc[tile][lane][i];
      aL[i] += pacc[tile][lane][4 + i];
    }
#pragma unroll
    for (int i = 0; i < 4; ++i) {
      int row = r0 + tile * 16 + q * 4 + i;
      outg[((size_t)(b * GN + row)) * GC + c] =
          fdiv_fast(acc[i], fmaxf(aL[i], 1e-30f));
    }
  }
}

// ---------------------------------------------------------------------------
extern "C" void kernel_launch(void* const* d_in, const int* in_sizes, int n_in,
                              void* d_out, int out_size, void* d_ws, size_t ws_size,
                              hipStream_t stream) {
  (void)in_sizes; (void)n_in; (void)out_size;
  const float* x   = (const float*)d_in[0];
  const int*   adj = (const int*)d_in[1];
  const float* Whd = (const float*)d_in[2];
  const float* a1h = (const float*)d_in[3];
  const float* a2h = (const float*)d_in[4];
  const float* Wo  = (const float*)d_in[5];
  const float* a1o = (const float*)d_in[6];
  const float* a2o = (const float*)d_in[7];

  size_t off = 0;
  char* base = (char*)d_ws;
  unsigned* mw = (unsigned*)(base + off); off += (size_t)GB * GN * 16 * 4;       // 1 MB
  ushort* VT   = (ushort*)(base + off);   off += (size_t)GB * GH * GN * GFH * 2; // 16.8 MB
  ushort* xcb  = (ushort*)(base + off);   off += (size_t)GB * GN * 512 * 2;      // 16.8 MB
  ushort* WoT  = (ushort*)(base + off);   off += (size_t)GC * 512 * 2;           // 16 KB
  ushort* hT   = (ushort*)(base + off);   off += (size_t)GB * GC * GN * 2;       // 0.5 MB
  float* f1    = (float*)(base + off);    off += (size_t)GB * GH * GN * 4;       // 0.5 MB
  float* f2    = (float*)(base + off);    off += (size_t)GB * GH * GN * 4;       // 0.5 MB
  float* f1b   = (float*)(base + off);    off += (size_t)GB * GN * 4;
  float* f2b   = (float*)(base + off);    off += (size_t)GB * GN * 4;

  if (ws_size < off) return;

  hipLaunchKernelGGL(k_pack_gemm1, dim3(6145), dim3(256), 0, stream,
                     adj, mw, x, Whd, a1h, a2h, VT, f1, f2, Wo, WoT);
  hipLaunchKernelGGL(k_attn1, dim3(1024), dim3(256), 0, stream,
                     VT, mw, f1, f2, xcb);
  hipLaunchKernelGGL(k_gemm2, dim3(256), dim3(256), 0, stream,
                     xcb, WoT, a1o, a2o, hT, f1b, f2b);
  hipLaunchKernelGGL(k_attn2, dim3(512), dim3(256), 0, stream,
                     hT, mw, f1b, f2b, (float*)d_out);
}

// Round 15
// 144.658 us; speedup vs baseline: 1.5231x; 1.5231x over previous
//
#include <hip/hip_runtime.h>

// GAT batch: B=32, N=512, Fin=128, Fhid=64, H=8, C=16.  fp32 I/O.
// R28 = exact R25 revert (best measured: 144.99us).
// R27 lesson: barrier-free attn1 -> VGPR 256, occupancy 10.9%, 112us.
//   The register/barrier tradeoff is now measured at both extremes;
//   R16's barrier-phased low-reg form is the optimum.
// Config: K1 int4-pack + 64-row gemm blocks + adj-first dispatch;
//   attn1 R16 form; K3 grid 256; K4 K-split.
#define GB 32
#define GN 512
#define GFIN 128
#define GFH 64
#define GH 8
#define GC 16

typedef short short8 __attribute__((ext_vector_type(8)));   // 8 fp16 bits (MFMA A/B frag)
typedef float f32x4 __attribute__((ext_vector_type(4)));    // MFMA C/D frag
typedef _Float16 h2 __attribute__((ext_vector_type(2)));
typedef _Float16 half8 __attribute__((ext_vector_type(8)));

__device__ __forceinline__ ushort f2h(float f) {
  _Float16 h = (_Float16)f;                 // v_cvt_f16_f32 (RNE), 1 inst
  return __builtin_bit_cast(ushort, h);
}
__device__ __forceinline__ h2 cvt_pk(float a, float b) {
  return __builtin_bit_cast(h2, __builtin_amdgcn_cvt_pkrtz(a, b));
}
__device__ __forceinline__ unsigned pkh2(float a, float b) {
  return __builtin_bit_cast(unsigned, __builtin_amdgcn_cvt_pkrtz(a, b));
}
__device__ __forceinline__ short8 ones8() {
  short8 o;
#pragma unroll
  for (int i = 0; i < 8; ++i) o[i] = (short)0x3C00;  // fp16 1.0
  return o;
}
// Fast a/b: v_rcp_f32 (1 ulp) + mul — result feeds fp16, noise-level error.
__device__ __forceinline__ float fdiv_fast(float a, float b) {
  return a * __builtin_amdgcn_rcpf(b);
}
__device__ __forceinline__ f32x4 mfma_h(short8 a, short8 b, f32x4 c) {
  return __builtin_amdgcn_mfma_f32_16x16x32_f16(
      __builtin_bit_cast(half8, a), __builtin_bit_cast(half8, b), c, 0, 0, 0);
}

// 8 masked fp16 scores (4 packed pairs) for one row of 8 consecutive cols.
__device__ __forceinline__ uint4 score8(unsigned E1u, unsigned e1u,
                                        const h2* E2h, const h2* e2h,
                                        unsigned mb) {
  h2 E1h = __builtin_bit_cast(h2, E1u);
  h2 e1h = __builtin_bit_cast(h2, e1u);
  unsigned lo = (((mb & 0xFu) * 0x00204081u) & 0x01010101u) * 0xFFu;
  unsigned hi = (((mb >> 4) * 0x00204081u) & 0x01010101u) * 0xFFu;
  unsigned m0 = __builtin_amdgcn_perm(lo, lo, 0x01010000u);
  unsigned m1 = __builtin_amdgcn_perm(lo, lo, 0x03030202u);
  unsigned m2 = __builtin_amdgcn_perm(hi, hi, 0x01010000u);
  unsigned m3 = __builtin_amdgcn_perm(hi, hi, 0x03030202u);
  uint4 u;
  u.x = __builtin_bit_cast(unsigned,
          __builtin_elementwise_max(E1h * E2h[0], e1h * e2h[0])) & m0;
  u.y = __builtin_bit_cast(unsigned,
          __builtin_elementwise_max(E1h * E2h[1], e1h * e2h[1])) & m1;
  u.z = __builtin_bit_cast(unsigned,
          __builtin_elementwise_max(E1h * E2h[2], e1h * e2h[2])) & m2;
  u.w = __builtin_bit_cast(unsigned,
          __builtin_elementwise_max(E1h * E2h[3], e1h * e2h[3])) & m3;
  return u;
}

// ---------------------------------------------------------------------------
// K1: blocks [0,4096): adj bit-pack (int4 + shfl-OR; dispatched FIRST).
// Blocks [4096,6144): gemm1, 64 rows/block (V^T fp16 + fp32 f1/f2).
// Block 6144: W_out -> WoT fp16.
// ---------------------------------------------------------------------------
__global__ __launch_bounds__(256) void k_pack_gemm1(
    const int* __restrict__ adj, unsigned* __restrict__ mw,
    const float* __restrict__ xg, const float* __restrict__ Wg,
    const float* __restrict__ a1g, const float* __restrict__ a2g,
    ushort* __restrict__ VTg, float* __restrict__ f1g, float* __restrict__ f2g,
    const float* __restrict__ Wog, ushort* __restrict__ WoT) {
  __shared__ ushort Wt[64][136];
  __shared__ ushort xl[64][136];
  int blk = blockIdx.x;
  int tid = threadIdx.x;

  if (blk == 6144) {
    for (int i = tid; i < 512 * GC; i += 256) {
      int k = i & 511, cc = i >> 9;
      WoT[cc * 512 + k] = f2h(Wog[(size_t)k * GC + cc]);
    }
    return;
  }
  if (blk < 4096) {                      // adj pack (HBM/L3 long pole)
    int pblk = blk;
    int4 v0 = *(const int4*)&adj[(size_t)pblk * 2048 + tid * 4];
    int4 v1 = *(const int4*)&adj[(size_t)pblk * 2048 + 1024 + tid * 4];
    int sh = 4 * (tid & 7);
    unsigned b0 = ((v0.x > 0) ? 1u : 0u) | ((v0.y > 0) ? 2u : 0u) |
                  ((v0.z > 0) ? 4u : 0u) | ((v0.w > 0) ? 8u : 0u);
    unsigned b1 = ((v1.x > 0) ? 1u : 0u) | ((v1.y > 0) ? 2u : 0u) |
                  ((v1.z > 0) ? 4u : 0u) | ((v1.w > 0) ? 8u : 0u);
    unsigned m0 = b0 << sh, m1 = b1 << sh;
    m0 |= __shfl_xor(m0, 1); m1 |= __shfl_xor(m1, 1);
    m0 |= __shfl_xor(m0, 2); m1 |= __shfl_xor(m1, 2);
    m0 |= __shfl_xor(m0, 4); m1 |= __shfl_xor(m1, 4);
    if ((tid & 7) == 0) {
      mw[pblk * 64 + (tid >> 3)] = m0;
      mw[pblk * 64 + 32 + (tid >> 3)] = m1;
    }
    return;
  }

  int gblk = blk - 4096;                 // gemm1: [0,2048), 64 rows each
  int bh = gblk >> 3, rs8 = gblk & 7;
  int b = bh >> 3, h = bh & 7;
  int r0 = rs8 * 64;
  int lane = tid & 63, w = tid >> 6;
  int c = lane & 15, q = lane >> 4;

  // W staging vectorized: 8 float4 iters/thread.
  const float* Wh = Wg + (size_t)h * GFIN * GFH;
  for (int u4 = tid; u4 < GFIN * GFH / 4; u4 += 256) {
    int i0 = u4 * 4;
    int f = i0 >> 6, j0 = i0 & 63;       // 4 | 64 -> all 4 share f
    float4 wv = *(const float4*)&Wh[i0];
    Wt[j0 + 0][f] = f2h(wv.x);
    Wt[j0 + 1][f] = f2h(wv.y);
    Wt[j0 + 2][f] = f2h(wv.z);
    Wt[j0 + 3][f] = f2h(wv.w);
  }
  const float* xb = xg + ((size_t)b * GN + r0) * GFIN;
  for (int u = tid; u < 64 * 32; u += 256) {
    int row = u >> 5, c4 = u & 31;
    float4 xf = *(const float4*)&xb[(size_t)row * GFIN + c4 * 4];
    uint2 us;
    us.x = pkh2(xf.x, xf.y);
    us.y = pkh2(xf.z, xf.w);
    *(uint2*)&xl[row][c4 * 4] = us;
  }
  __syncthreads();

  short8 Bf[4][4];
#pragma unroll
  for (int cb = 0; cb < 4; ++cb)
#pragma unroll
    for (int kk = 0; kk < 4; ++kk)
      Bf[cb][kk] = *(const short8*)&Wt[cb * 16 + c][kk * 32 + q * 8];

  float a1v[4], a2v[4];
#pragma unroll
  for (int cb = 0; cb < 4; ++cb) {
    a1v[cb] = a1g[h * 64 + cb * 16 + c];
    a2v[cb] = a2g[h * 64 + cb * 16 + c];
  }

  f32x4 acc[4];
#pragma unroll
  for (int cb = 0; cb < 4; ++cb) acc[cb] = (f32x4){0.f, 0.f, 0.f, 0.f};

#pragma unroll
  for (int kk = 0; kk < 4; ++kk) {
    short8 A = *(const short8*)&xl[w * 16 + c][kk * 32 + q * 8];
#pragma unroll
    for (int cb = 0; cb < 4; ++cb)
      acc[cb] = mfma_h(A, Bf[cb][kk], acc[cb]);
  }

  ushort* VT = VTg + (size_t)bh * GN * GFH;
  float* f1o = f1g + (size_t)bh * GN;
  float* f2o = f2g + (size_t)bh * GN;
  int rowb = r0 + w * 16 + q * 4;
  float v1[4] = {0.f, 0.f, 0.f, 0.f}, v2[4] = {0.f, 0.f, 0.f, 0.f};
#pragma unroll
  for (int cb = 0; cb < 4; ++cb) {
    f32x4 a = acc[cb];
    uint2 vs;
    vs.x = pkh2(a[0], a[1]);
    vs.y = pkh2(a[2], a[3]);
    *(uint2*)&VT[(size_t)(cb * 16 + c) * GN + rowb] = vs;
#pragma unroll
    for (int i = 0; i < 4; ++i) {
      v1[i] += a[i] * a1v[cb];
      v2[i] += a[i] * a2v[cb];
    }
  }
#pragma unroll
  for (int i = 0; i < 4; ++i) {
#pragma unroll
    for (int off = 1; off < 16; off <<= 1) {
      v1[i] += __shfl_xor(v1[i], off);
      v2[i] += __shfl_xor(v2[i], off);
    }
    if (c == 0) { f1o[rowb + i] = v1[i]; f2o[rowb + i] = v2[i]; }
  }
}

// ---------------------------------------------------------------------------
// K2: layer-1 attention (R16 form): 128 rows/block (4 slices), 16-row dbuf
// P, 4 blocks/CU, ones-MFMA row sums, fast-rcp epilogue, mask prefetch,
// packed-fp16 score gen + readlane broadcasts. grid 1024.
// ---------------------------------------------------------------------------
__global__ __launch_bounds__(256, 4) void k_attn1(
    const ushort* __restrict__ VTg, const unsigned* __restrict__ mwg,
    const float* __restrict__ f1g, const float* __restrict__ f2g,
    ushort* __restrict__ xcb) {
  __shared__ ushort P[2][16][520];       // 33.3 KB double buffer
  int blk = blockIdx.x;
  int bh = blk & 255, slice = blk >> 8;  // slice 0..3
  int b = bh >> 3, h = bh & 7;
  int r0 = slice * 128;
  int tid = threadIdx.x, lane = tid & 63, w = tid >> 6;
  int c = lane & 15, q = lane >> 4;

  const unsigned* mwb = mwg + (size_t)b * GN * 16;
  const float* f1w = f1g + (size_t)bh * GN;
  const float* f2w = f2g + (size_t)bh * GN;

  float4 fa = *(const float4*)&f2w[lane * 8];
  float4 fb = *(const float4*)&f2w[lane * 8 + 4];
  h2 E2h[4], e2h[4];
  {
    float f2v[8] = {fa.x, fa.y, fa.z, fa.w, fb.x, fb.y, fb.z, fb.w};
#pragma unroll
    for (int j = 0; j < 4; ++j) {
      E2h[j] = cvt_pk(__expf(f2v[2 * j]), __expf(f2v[2 * j + 1]));
      e2h[j] = cvt_pk(__expf(0.2f * f2v[2 * j]), __expf(0.2f * f2v[2 * j + 1]));
    }
  }
  // e^-4 folded into f1 side: keeps exp products in fp16 range; ratio
  // invariant. 128 rows/block -> two packed banks, selected by row>>6.
  float f1a = f1w[r0 + lane];
  float f1b = f1w[r0 + 64 + lane];
  unsigned E1pk0 = pkh2(__expf(f1a - 4.f), __expf(f1a - 4.f));
  unsigned e1pk0 = pkh2(__expf(0.2f * f1a - 4.f), __expf(0.2f * f1a - 4.f));
  unsigned E1pk1 = pkh2(__expf(f1b - 4.f), __expf(f1b - 4.f));
  unsigned e1pk1 = pkh2(__expf(0.2f * f1b - 4.f), __expf(0.2f * f1b - 4.f));

  const ushort* VT = VTg + (size_t)bh * GN * GFH + (size_t)(w * 16 + c) * GN + q * 8;
  short8 Bf[16];
#pragma unroll
  for (int kk = 0; kk < 16; ++kk) Bf[kk] = *(const short8*)&VT[kk * 32];
  const short8 ONES = ones8();

  unsigned mn[4];
#pragma unroll
  for (int ri = 0; ri < 4; ++ri)
    mn[ri] = mwb[(size_t)(r0 + w + 4 * ri) * 16 + (lane >> 2)];
#pragma unroll
  for (int ri = 0; ri < 4; ++ri) {
    unsigned E1u = (unsigned)__builtin_amdgcn_readlane((int)E1pk0, w + 4 * ri);
    unsigned e1u = (unsigned)__builtin_amdgcn_readlane((int)e1pk0, w + 4 * ri);
    unsigned mb = (mn[ri] >> (8 * (lane & 3))) & 0xffu;
    uint4 u = score8(E1u, e1u, E2h, e2h, mb);
    *(uint4*)&P[0][w + 4 * ri][lane * 8] = u;
  }
#pragma unroll
  for (int ri = 0; ri < 4; ++ri)
    mn[ri] = mwb[(size_t)(r0 + 16 + w + 4 * ri) * 16 + (lane >> 2)];
  __syncthreads();

#pragma unroll
  for (int t = 0; t < 8; ++t) {
    int tb = r0 + t * 16;
    const ushort (*Pc)[520] = P[t & 1];

    f32x4 acc = (f32x4){0.f, 0.f, 0.f, 0.f};
    f32x4 aL = (f32x4){0.f, 0.f, 0.f, 0.f};
#pragma unroll
    for (int kk = 0; kk < 16; ++kk) {
      short8 A = *(const short8*)&Pc[c][kk * 32 + q * 8];
      acc = mfma_h(A, Bf[kk], acc);
      aL  = mfma_h(A, ONES, aL);
    }

    if (t < 7) {
      int rowbase = (t + 1) * 16;          // 16..112, uniform
#pragma unroll
      for (int ri = 0; ri < 4; ++ri) {
        int row = rowbase + w + 4 * ri;    // uniform per wave
        unsigned E1u, e1u;
        if (row < 64) {
          E1u = (unsigned)__builtin_amdgcn_readlane((int)E1pk0, row);
          e1u = (unsigned)__builtin_amdgcn_readlane((int)e1pk0, row);
        } else {
          E1u = (unsigned)__builtin_amdgcn_readlane((int)E1pk1, row - 64);
          e1u = (unsigned)__builtin_amdgcn_readlane((int)e1pk1, row - 64);
        }
        unsigned mb = (mn[ri] >> (8 * (lane & 3))) & 0xffu;
        uint4 u = score8(E1u, e1u, E2h, e2h, mb);
        *(uint4*)&P[(t + 1) & 1][w + 4 * ri][lane * 8] = u;
      }
      if (t < 6) {
#pragma unroll
        for (int ri = 0; ri < 4; ++ri)
          mn[ri] = mwb[(size_t)(tb + 32 + w + 4 * ri) * 16 + (lane >> 2)];
      }
    }

#pragma unroll
    for (int i = 0; i < 4; ++i) {
      int row = tb + q * 4 + i;
      float v = fdiv_fast(acc[i], fmaxf(aL[i], 1e-30f));
      v = v > 0.f ? v : __expf(v) - 1.f;            // elu
      xcb[((size_t)(b * GN + row)) * 512 + h * 64 + w * 16 + c] = f2h(v);
    }
    __syncthreads();
  }
}

// ---------------------------------------------------------------------------
// K3: gemm2 via MFMA, A-frags straight from L2-resident xcb. grid = 256.
// ---------------------------------------------------------------------------
__global__ __launch_bounds__(256) void k_gemm2(
    const ushort* __restrict__ xcb, const ushort* __restrict__ WoT,
    const float* __restrict__ a1o, const float* __restrict__ a2o,
    ushort* __restrict__ hTg, float* __restrict__ f1bg,
    float* __restrict__ f2bg) {
  int vb = blockIdx.x;
  int b = vb >> 3, r0 = (vb & 7) * 64;
  int tid = threadIdx.x, lane = tid & 63, w = tid >> 6;
  int c = lane & 15, q = lane >> 4;

  short8 Bf[16];
#pragma unroll
  for (int kk = 0; kk < 16; ++kk)
    Bf[kk] = *(const short8*)&WoT[(size_t)c * 512 + kk * 32 + q * 8];

  const ushort* xrow = xcb + ((size_t)(b * GN + r0 + w * 16 + c)) * 512 + q * 8;
  f32x4 acc = (f32x4){0.f, 0.f, 0.f, 0.f};
#pragma unroll
  for (int kk = 0; kk < 16; ++kk) {
    short8 A = *(const short8*)&xrow[kk * 32];
    acc = mfma_h(A, Bf[kk], acc);
  }

  float a1v = a1o[c], a2v = a2o[c];
  int rowb = r0 + w * 16 + q * 4;
  uint2 vs;
  vs.x = pkh2(acc[0], acc[1]);
  vs.y = pkh2(acc[2], acc[3]);
  *(uint2*)&hTg[((size_t)b * GC + c) * 512 + rowb] = vs;
#pragma unroll
  for (int i = 0; i < 4; ++i) {
    float v1 = acc[i] * a1v, v2 = acc[i] * a2v;
#pragma unroll
    for (int off = 1; off < 16; off <<= 1) {
      v1 += __shfl_xor(v1, off);
      v2 += __shfl_xor(v2, off);
    }
    if (c == 0) {
      f1bg[(size_t)b * GN + rowb + i] = v1;
      f2bg[(size_t)b * GN + rowb + i] = v2;
    }
  }
}

// ---------------------------------------------------------------------------
// K4: layer-2 attention: grid = 512 (b*16 + 32-row tile). ALL 4 waves
// in the MFMA phase via K-split: wave w computes tile (w&1) over K-half
// (w>>1) (8+8 MFMAs); partials combined via 4KB LDS.
// ---------------------------------------------------------------------------
__global__ __launch_bounds__(256) void k_attn2(
    const ushort* __restrict__ hTg, const unsigned* __restrict__ mwg,
    const float* __restrict__ f1g, const float* __restrict__ f2g,
    float* __restrict__ outg) {
  __shared__ ushort P[32][520];
  __shared__ float pacc[2][64][8];     // [tile][lane][acc0..3, aL0..3]
  int vb = blockIdx.x;
  int b = vb >> 4, r0 = (vb & 15) * 32;
  int tid = threadIdx.x, lane = tid & 63, w = tid >> 6;
  int c = lane & 15, q = lane >> 4;
  const short8 ONES = ones8();

  const unsigned* mwb = mwg + (size_t)b * GN * 16;
  const float* f1w = f1g + (size_t)b * GN;
  const float* f2w = f2g + (size_t)b * GN;

  float4 fa = *(const float4*)&f2w[lane * 8];
  float4 fb = *(const float4*)&f2w[lane * 8 + 4];
  h2 E2h[4], e2h[4];
  {
    float f2v[8] = {fa.x, fa.y, fa.z, fa.w, fb.x, fb.y, fb.z, fb.w};
#pragma unroll
    for (int j = 0; j < 4; ++j) {
      E2h[j] = cvt_pk(__expf(f2v[2 * j]), __expf(f2v[2 * j + 1]));
      e2h[j] = cvt_pk(__expf(0.2f * f2v[2 * j]), __expf(0.2f * f2v[2 * j + 1]));
    }
  }
  float f1v = 0.f;
  if (lane < 8) f1v = f1w[r0 + w * 8 + lane];
  float E1f = __expf(f1v - 4.f), e1f = __expf(0.2f * f1v - 4.f);
  unsigned E1pk = pkh2(E1f, E1f);
  unsigned e1pk = pkh2(e1f, e1f);

  unsigned mword[8];
#pragma unroll
  for (int ri = 0; ri < 8; ++ri)
    mword[ri] = mwb[(size_t)(r0 + w * 8 + ri) * 16 + (lane >> 2)];
#pragma unroll
  for (int ri = 0; ri < 8; ++ri) {
    unsigned E1u = (unsigned)__builtin_amdgcn_readlane((int)E1pk, ri);
    unsigned e1u = (unsigned)__builtin_amdgcn_readlane((int)e1pk, ri);
    unsigned mb = (mword[ri] >> (8 * (lane & 3))) & 0xffu;
    uint4 u = score8(E1u, e1u, E2h, e2h, mb);
    *(uint4*)&P[w * 8 + ri][lane * 8] = u;
  }
  __syncthreads();

  int tile = w & 1, kh = w >> 1;       // tile 0/1, K-half 0/1
  short8 Bf[8];
#pragma unroll
  for (int kk = 0; kk < 8; ++kk)
    Bf[kk] = *(const short8*)&hTg[((size_t)b * GC + c) * 512 +
                                  (kh * 8 + kk) * 32 + q * 8];
  f32x4 acc = (f32x4){0.f, 0.f, 0.f, 0.f};
  f32x4 aL = (f32x4){0.f, 0.f, 0.f, 0.f};
#pragma unroll
  for (int kk = 0; kk < 8; ++kk) {
    short8 A = *(const short8*)&P[tile * 16 + c][(kh * 8 + kk) * 32 + q * 8];
    acc = mfma_h(A, Bf[kk], acc);
    aL  = mfma_h(A, ONES, aL);
  }
  if (kh == 1) {
#pragma unroll
    for (int i = 0; i < 4; ++i) {
      pacc[tile][lane][i] = acc[i];
      pacc[tile][lane][4 + i] = aL[i];
    }
  }
  __syncthreads();
  if (kh == 0) {
#pragma unroll
    for (int i = 0; i < 4; ++i) {
      acc[i] += pacc[tile][lane][i];
      aL[i] += pacc[tile][lane][4 + i];
    }
#pragma unroll
    for (int i = 0; i < 4; ++i) {
      int row = r0 + tile * 16 + q * 4 + i;
      outg[((size_t)(b * GN + row)) * GC + c] =
          fdiv_fast(acc[i], fmaxf(aL[i], 1e-30f));
    }
  }
}

// ---------------------------------------------------------------------------
extern "C" void kernel_launch(void* const* d_in, const int* in_sizes, int n_in,
                              void* d_out, int out_size, void* d_ws, size_t ws_size,
                              hipStream_t stream) {
  (void)in_sizes; (void)n_in; (void)out_size;
  const float* x   = (const float*)d_in[0];
  const int*   adj = (const int*)d_in[1];
  const float* Whd = (const float*)d_in[2];
  const float* a1h = (const float*)d_in[3];
  const float* a2h = (const float*)d_in[4];
  const float* Wo  = (const float*)d_in[5];
  const float* a1o = (const float*)d_in[6];
  const float* a2o = (const float*)d_in[7];

  size_t off = 0;
  char* base = (char*)d_ws;
  unsigned* mw = (unsigned*)(base + off); off += (size_t)GB * GN * 16 * 4;       // 1 MB
  ushort* VT   = (ushort*)(base + off);   off += (size_t)GB * GH * GN * GFH * 2; // 16.8 MB
  ushort* xcb  = (ushort*)(base + off);   off += (size_t)GB * GN * 512 * 2;      // 16.8 MB
  ushort* WoT  = (ushort*)(base + off);   off += (size_t)GC * 512 * 2;           // 16 KB
  ushort* hT   = (ushort*)(base + off);   off += (size_t)GB * GC * GN * 2;       // 0.5 MB
  float* f1    = (float*)(base + off);    off += (size_t)GB * GH * GN * 4;       // 0.5 MB
  float* f2    = (float*)(base + off);    off += (size_t)GB * GH * GN * 4;       // 0.5 MB
  float* f1b   = (float*)(base + off);    off += (size_t)GB * GN * 4;
  float* f2b   = (float*)(base + off);    off += (size_t)GB * GN * 4;

  if (ws_size < off) return;

  hipLaunchKernelGGL(k_pack_gemm1, dim3(6145), dim3(256), 0, stream,
                     adj, mw, x, Whd, a1h, a2h, VT, f1, f2, Wo, WoT);
  hipLaunchKernelGGL(k_attn1, dim3(1024), dim3(256), 0, stream,
                     VT, mw, f1, f2, xcb);
  hipLaunchKernelGGL(k_gemm2, dim3(256), dim3(256), 0, stream,
                     xcb, WoT, a1o, a2o, hT, f1b, f2b);
  hipLaunchKernelGGL(k_attn2, dim3(512), dim3(256), 0, stream,
                     hT, mw, f1b, f2b, (float*)d_out);
}